// Round 5
// baseline (50.085 us; speedup 1.0000x reference)
//
#include <hip/hip_runtime.h>
#include <hip/hip_bf16.h>

#define TOK_S    4096
#define NBI      1089      // 33*33
#define NBI_P    1092      // LDS pad
#define KP_BI    1120      // A-matrix K padded to multiple of 32
#define NTRI     512
#define NTRI_P   544       // 512 real bins + 32 dump slots
#define NHID     256
#define NROWS    4096
#define HSTRIDE  (NHID + 4)   // 260: LDS pad for conflict-free reads

#define HIST_BLKS   (NROWS / 2)                       // 2048
#define TRANS_ELEMS (NHID * KP_BI + NHID * NTRI)      // 417792
#define TRANS_BLKS  (TRANS_ELEMS / 1024)              // 408 (exact)

typedef __attribute__((ext_vector_type(8))) short short8;   // 8 bf16
typedef __attribute__((ext_vector_type(4))) float f32x4;

// ============ K1: branch-free histograms (2 rows/block) + weight transpose ============
__global__ __launch_bounds__(256)
void hist_trans(const int* __restrict__ src,
                const float* __restrict__ Wb1, const float* __restrict__ Wt1,
                __hip_bfloat16* __restrict__ Abi,
                __hip_bfloat16* __restrict__ Atri,
                __hip_bfloat16* __restrict__ WbT,
                __hip_bfloat16* __restrict__ WtT,
                float* __restrict__ inv)
{
    __shared__ int   s_bi [2][NBI_P];    // 8736 B
    __shared__ int   s_tri[2][NTRI_P];   // 4352 B
    __shared__ float s_ps [2][2][2];

    const int tid = threadIdx.x;

    // ---- transpose blocks (appended after hist blocks) ----
    if (blockIdx.x >= HIST_BLKS) {
        int base = (blockIdx.x - HIST_BLKS) * 1024 + tid;
        const int nb = NHID * KP_BI;
        #pragma unroll
        for (int i = 0; i < 4; ++i) {
            int idx = base + i * 256;
            if (idx < nb) {
                int c = idx / KP_BI, k = idx - c * KP_BI;
                WbT[idx] = __float2bfloat16(k < NBI ? Wb1[k * NHID + c] : 0.0f);
            } else {
                int j = idx - nb;                    // < NHID*NTRI by construction
                int c = j >> 9, k = j & 511;
                WtT[j] = __float2bfloat16(Wt1[k * NHID + c]);
            }
        }
        return;
    }

    // ---- histogram blocks ----
    const int wave = tid >> 6;
    const int lane = tid & 63;
    const int wrow = wave >> 1;          // row within block (0/1)
    const int wpar = wave & 1;           // half of the row
    const size_t row = (size_t)blockIdx.x * 2 + wrow;
    const int dump = NTRI + (lane & 31); // per-lane trigram dump slot

    for (int i = tid; i < 2 * NBI_P;  i += 256) ((int*)s_bi)[i]  = 0;
    for (int i = tid; i < 2 * NTRI_P; i += 256) ((int*)s_tri)[i] = 0;
    __syncthreads();

    int* bi  = s_bi[wrow];
    int* tri = s_tri[wrow];
    const int4* rowp = (const int4*)(src + row * TOK_S);
    const int*  rowt = src + row * TOK_S;

    #pragma unroll
    for (int j = 0; j < 8; ++j) {
        const int idx = wpar * 512 + j * 64 + lane;
        int4 c = rowp[idx];
        int e0 = 0, e1 = 0;
        if (idx != 1023) {               // tokens idx*4+4, +5 (OOB-guarded)
            const int2 e = *(const int2*)(rowt + idx * 4 + 4);
            e0 = e.x; e1 = e.y;
        }
        // bigram: NO masks. Invalid pairs land in row 0 / col 0 of the 33x33
        // grid (c1==0 -> bins 0..32, c2==0 -> bins k*33); zeroed at export.
        const int b0 = c.x * 33 + c.y;
        const int b1 = c.y * 33 + c.z;
        const int b2 = c.z * 33 + c.w;
        const int b3 = c.w * 33 + e0;
        atomicAdd(&bi[b0], 1);
        atomicAdd(&bi[b1], 1);
        atomicAdd(&bi[b2], 1);
        atomicAdd(&bi[b3], 1);
        // trigram: unconditional atomic; invalid -> per-lane dump slot
        const int m0 = min(min(c.x, c.y), c.z);
        const int m1 = min(min(c.y, c.z), c.w);
        const int m2 = min(min(c.z, c.w), e0);
        const int m3 = min(min(c.w, e0), e1);
        const int t0 = (m0 > 0) ? ((b0 * 33 + c.z) & 511) : dump;
        const int t1 = (m1 > 0) ? ((b1 * 33 + c.w) & 511) : dump;
        const int t2 = (m2 > 0) ? ((b2 * 33 + e0) & 511) : dump;
        const int t3 = (m3 > 0) ? ((b3 * 33 + e1) & 511) : dump;
        atomicAdd(&tri[t0], 1);
        atomicAdd(&tri[t1], 1);
        atomicAdd(&tri[t2], 1);
        atomicAdd(&tri[t3], 1);
    }
    __syncthreads();

    // export: zero invalid bigram bins; len = sum of valid bins
    float bsum = 0.0f, tsum = 0.0f;
    __hip_bfloat16* arow = Abi + row * KP_BI;
    for (int i = wpar * 64 + lane; i < KP_BI; i += 128) {
        float f = 0.0f;
        if (i < NBI) {
            int v = bi[i];
            f = (i >= 33 && (i % 33) != 0) ? (float)v : 0.0f;
        }
        bsum += f;
        arow[i] = __float2bfloat16(f);
    }
    __hip_bfloat16* trow = Atri + row * NTRI;
    for (int i = wpar * 64 + lane; i < NTRI; i += 128) {
        float f = (float)tri[i];
        tsum += f;
        trow[i] = __float2bfloat16(f);
    }
    #pragma unroll
    for (int s = 32; s; s >>= 1) {
        bsum += __shfl_xor(bsum, s, 64);
        tsum += __shfl_xor(tsum, s, 64);
    }
    if (lane == 0) { s_ps[wrow][wpar][0] = bsum; s_ps[wrow][wpar][1] = tsum; }
    __syncthreads();
    if (tid < 2) {
        float bs = s_ps[tid][0][0] + s_ps[tid][1][0];
        float ts = s_ps[tid][0][1] + s_ps[tid][1][1];
        size_t r2 = ((size_t)blockIdx.x * 2 + tid) * 2;
        inv[r2 + 0] = 1.0f / fmaxf(bs, 1.0f);
        inv[r2 + 1] = 1.0f / fmaxf(ts, 1.0f);
    }
}

// ============ K2: fused layer1 MFMA GEMM (BM=32, N=256) + relu/len + layer2 ============
template<int KP>
__device__ __forceinline__
void head_body(const __hip_bfloat16* __restrict__ A,
               const __hip_bfloat16* __restrict__ WT,
               const float* __restrict__ b1,
               const float* __restrict__ W2,
               const float* __restrict__ b2,
               const float* __restrict__ inv, const int invoff, const int headoff,
               float* __restrict__ out, const int m0,
               float (*sH)[HSTRIDE])
{
    const int wave = threadIdx.x >> 6;       // 8 waves
    const int lane = threadIdx.x & 63;
    const int wn   = wave * 32;              // 32-col strip of N=256
    const int fr   = lane & 15;
    const int kg   = lane >> 4;

    const __hip_bfloat16* A0 = A  + (size_t)(m0 + fr) * KP + kg * 8;
    const __hip_bfloat16* A1 = A0 + (size_t)16 * KP;
    const __hip_bfloat16* B0 = WT + (size_t)(wn + fr) * KP + kg * 8;
    const __hip_bfloat16* B1 = B0 + (size_t)16 * KP;

    f32x4 acc00 = {}, acc01 = {}, acc10 = {}, acc11 = {};
    #pragma unroll 4
    for (int k = 0; k < KP; k += 32) {
        short8 a0  = *(const short8*)(A0 + k);
        short8 a1  = *(const short8*)(A1 + k);
        short8 b0  = *(const short8*)(B0 + k);
        short8 b1v = *(const short8*)(B1 + k);
        acc00 = __builtin_amdgcn_mfma_f32_16x16x32_bf16(a0, b0,  acc00, 0, 0, 0);
        acc01 = __builtin_amdgcn_mfma_f32_16x16x32_bf16(a0, b1v, acc01, 0, 0, 0);
        acc10 = __builtin_amdgcn_mfma_f32_16x16x32_bf16(a1, b0,  acc10, 0, 0, 0);
        acc11 = __builtin_amdgcn_mfma_f32_16x16x32_bf16(a1, b1v, acc11, 0, 0, 0);
    }

    // D layout: col = lane&15 (B side), row = (lane>>4)*4 + reg (A side)
    f32x4 accs[2][2] = { {acc00, acc01}, {acc10, acc11} };
    #pragma unroll
    for (int mf = 0; mf < 2; ++mf) {
        #pragma unroll
        for (int nf = 0; nf < 2; ++nf) {
            const int col = wn + nf * 16 + fr;
            const float bias = b1[col];
            #pragma unroll
            for (int r = 0; r < 4; ++r) {
                const int rl = mf * 16 + kg * 4 + r;
                const float iv = inv[(m0 + rl) * 2 + invoff];
                sH[rl][col] = fmaxf(fmaf(accs[mf][nf][r], iv, bias), 0.0f);
            }
        }
    }
    __syncthreads();

    // ---- layer 2: 32 rows x 32 outs, 2 outs/thread ----
    const int r  = threadIdx.x >> 4;         // 0..31
    const int oo = threadIdx.x & 15;
    const float* hr = sH[r];
    float a0 = b2[oo], a1 = b2[oo + 16];
    #pragma unroll 8
    for (int j = 0; j < NHID; j += 4) {
        float4 h = *(const float4*)(hr + j);
        a0 = fmaf(h.x, W2[(j + 0) * 32 + oo], a0);
        a0 = fmaf(h.y, W2[(j + 1) * 32 + oo], a0);
        a0 = fmaf(h.z, W2[(j + 2) * 32 + oo], a0);
        a0 = fmaf(h.w, W2[(j + 3) * 32 + oo], a0);
        a1 = fmaf(h.x, W2[(j + 0) * 32 + oo + 16], a1);
        a1 = fmaf(h.y, W2[(j + 1) * 32 + oo + 16], a1);
        a1 = fmaf(h.z, W2[(j + 2) * 32 + oo + 16], a1);
        a1 = fmaf(h.w, W2[(j + 3) * 32 + oo + 16], a1);
    }
    const size_t ro = (size_t)(m0 + r) * 64 + headoff;
    out[ro + oo]      = a0;
    out[ro + oo + 16] = a1;
}

__global__ __launch_bounds__(512, 1)
void gemm_fused(const __hip_bfloat16* __restrict__ Abi,
                const __hip_bfloat16* __restrict__ WbT,
                const float* __restrict__ bb1,
                const float* __restrict__ Wb2, const float* __restrict__ bb2,
                const __hip_bfloat16* __restrict__ Atri,
                const __hip_bfloat16* __restrict__ WtT,
                const float* __restrict__ bt1,
                const float* __restrict__ Wt2, const float* __restrict__ bt2,
                const float* __restrict__ inv,
                float* __restrict__ out)
{
    __shared__ float sH[32][HSTRIDE];        // 33.3 KB
    const int bid = blockIdx.x;
    if (bid < NROWS / 32) {
        head_body<KP_BI>(Abi, WbT, bb1, Wb2, bb2, inv, 0, 0,  out, bid * 32, sH);
    } else {
        head_body<NTRI>(Atri, WtT, bt1, Wt2, bt2, inv, 1, 32, out, (bid - NROWS / 32) * 32, sH);
    }
}

// ============ launcher ============
extern "C" void kernel_launch(void* const* d_in, const int* in_sizes, int n_in,
                              void* d_out, int out_size, void* d_ws, size_t ws_size,
                              hipStream_t stream) {
    const int*   src = (const int*)  d_in[0];
    const float* Wb1 = (const float*)d_in[1];
    const float* bb1 = (const float*)d_in[2];
    const float* Wb2 = (const float*)d_in[3];
    const float* bb2 = (const float*)d_in[4];
    const float* Wt1 = (const float*)d_in[5];
    const float* bt1 = (const float*)d_in[6];
    const float* Wt2 = (const float*)d_in[7];
    const float* bt2 = (const float*)d_in[8];
    float* outp = (float*)d_out;

    const int B = in_sizes[0] / TOK_S;           // 4096 rows

    char* ws = (char*)d_ws;
    __hip_bfloat16* Abi  = (__hip_bfloat16*)(ws);
    __hip_bfloat16* Atri = (__hip_bfloat16*)(ws + (size_t)B * KP_BI * 2);
    char* ws2 = ws + (size_t)B * KP_BI * 2 + (size_t)B * NTRI * 2;
    __hip_bfloat16* WbT  = (__hip_bfloat16*)(ws2);
    __hip_bfloat16* WtT  = (__hip_bfloat16*)(ws2 + (size_t)NHID * KP_BI * 2);
    float* inv = (float*)(ws2 + (size_t)NHID * KP_BI * 2 + (size_t)NHID * NTRI * 2);

    hist_trans<<<HIST_BLKS + TRANS_BLKS, 256, 0, stream>>>(
        src, Wb1, Wt1, Abi, Atri, WbT, WtT, inv);

    gemm_fused<<<2 * (B / 32), 512, 0, stream>>>(
        Abi, WbT, bb1, Wb2, bb2, Atri, WtT, bt1, Wt2, bt2, inv, outp);
}

// Round 6
// 47.898 us; speedup vs baseline: 1.0457x; 1.0457x over previous
//
#include <hip/hip_runtime.h>
#include <hip/hip_bf16.h>

#define TOK_S    4096
#define NBI      1089      // 33*33
#define NBI_P    1092      // LDS pad (mult of 4)
#define KP_BI    1120      // A-matrix K padded to multiple of 32
#define NTRI     512
#define NTRI_P   544       // 512 real bins + 32 dump slots
#define NHID     256
#define NROWS    4096
#define HSTRIDE  (NHID + 4)

#define HIST_BLKS   (NROWS / 2)                       // 2048
#define TRANS_ELEMS (NHID * KP_BI + NHID * NTRI)      // 417792
#define TRANS_BLKS  (TRANS_ELEMS / 1024)              // 408 (exact)

typedef __attribute__((ext_vector_type(8))) short short8;   // 8 bf16
typedef __attribute__((ext_vector_type(4))) float f32x4;

static __device__ __forceinline__ unsigned int f2bf(float f) {
    __hip_bfloat16 h = __float2bfloat16(f);
    return (unsigned int)*reinterpret_cast<unsigned short*>(&h);
}

// ============ K1: histograms (2 rows/block, 8-tok groups, hoisted loads) ============
__global__ __launch_bounds__(256, 4)
void hist_trans(const int* __restrict__ src,
                const float* __restrict__ Wb1, const float* __restrict__ Wt1,
                __hip_bfloat16* __restrict__ Abi,
                __hip_bfloat16* __restrict__ Atri,
                __hip_bfloat16* __restrict__ WbT,
                __hip_bfloat16* __restrict__ WtT,
                float* __restrict__ inv)
{
    __shared__ int   s_bi [2][NBI_P];    // 8736 B
    __shared__ int   s_tri[2][NTRI_P];   // 4352 B
    __shared__ float s_ps [2][2][2];

    const int tid = threadIdx.x;

    // ---- transpose blocks (appended after hist blocks) ----
    if (blockIdx.x >= HIST_BLKS) {
        int base = (blockIdx.x - HIST_BLKS) * 1024 + tid;
        const int nb = NHID * KP_BI;
        #pragma unroll
        for (int i = 0; i < 4; ++i) {
            int idx = base + i * 256;
            if (idx < nb) {
                int c = idx / KP_BI, k = idx - c * KP_BI;
                WbT[idx] = __float2bfloat16(k < NBI ? Wb1[k * NHID + c] : 0.0f);
            } else {
                int j = idx - nb;
                int c = j >> 9, k = j & 511;
                WtT[j] = __float2bfloat16(Wt1[k * NHID + c]);
            }
        }
        return;
    }

    // ---- histogram blocks ----
    const int wave = tid >> 6;
    const int lane = tid & 63;
    const int wrow = wave >> 1;          // row within block (0/1)
    const int wpar = wave & 1;           // half of the row
    const size_t row = (size_t)blockIdx.x * 2 + wrow;
    const int dump = NTRI + (lane & 31);

    // vectorized zero
    for (int i = tid; i < 2 * NBI_P / 4;  i += 256) ((int4*)s_bi)[i]  = int4{0,0,0,0};
    for (int i = tid; i < 2 * NTRI_P / 4; i += 256) ((int4*)s_tri)[i] = int4{0,0,0,0};
    __syncthreads();

    int* bi  = s_bi[wrow];
    int* tri = s_tri[wrow];
    const int4* rowp = (const int4*)(src + row * TOK_S);
    const int*  rowt = src + row * TOK_S;

    // hoist ALL loads: 4 groups of 8 tokens (+2 overlap) per lane
    int4 A[4], Bv[4];
    int2 E[4];
    #pragma unroll
    for (int jj = 0; jj < 4; ++jj) {
        const int idx = wpar * 256 + jj * 64 + lane;   // group index in [0,512)
        A[jj]  = rowp[2 * idx];
        Bv[jj] = rowp[2 * idx + 1];
        if (idx != 511) E[jj] = *(const int2*)(rowt + 8 * idx + 8);  // 8B-aligned
        else            E[jj] = int2{0, 0};
    }

    #pragma unroll
    for (int jj = 0; jj < 4; ++jj) {
        const int t0 = A[jj].x, t1 = A[jj].y, t2 = A[jj].z, t3 = A[jj].w;
        const int t4 = Bv[jj].x, t5 = Bv[jj].y, t6 = Bv[jj].z, t7 = Bv[jj].w;
        const int t8 = E[jj].x, t9 = E[jj].y;
        const int b0 = t0 * 33 + t1;
        const int b1 = t1 * 33 + t2;
        const int b2 = t2 * 33 + t3;
        const int b3 = t3 * 33 + t4;
        const int b4 = t4 * 33 + t5;
        const int b5 = t5 * 33 + t6;
        const int b6 = t6 * 33 + t7;
        const int b7 = t7 * 33 + t8;
        atomicAdd(&bi[b0], 1);  atomicAdd(&bi[b1], 1);
        atomicAdd(&bi[b2], 1);  atomicAdd(&bi[b3], 1);
        atomicAdd(&bi[b4], 1);  atomicAdd(&bi[b5], 1);
        atomicAdd(&bi[b6], 1);  atomicAdd(&bi[b7], 1);
        const int u0 = (min(min(t0, t1), t2) > 0) ? ((b0 * 33 + t2) & 511) : dump;
        const int u1 = (min(min(t1, t2), t3) > 0) ? ((b1 * 33 + t3) & 511) : dump;
        const int u2 = (min(min(t2, t3), t4) > 0) ? ((b2 * 33 + t4) & 511) : dump;
        const int u3 = (min(min(t3, t4), t5) > 0) ? ((b3 * 33 + t5) & 511) : dump;
        const int u4 = (min(min(t4, t5), t6) > 0) ? ((b4 * 33 + t6) & 511) : dump;
        const int u5 = (min(min(t5, t6), t7) > 0) ? ((b5 * 33 + t7) & 511) : dump;
        const int u6 = (min(min(t6, t7), t8) > 0) ? ((b6 * 33 + t8) & 511) : dump;
        const int u7 = (min(min(t7, t8), t9) > 0) ? ((b7 * 33 + t9) & 511) : dump;
        atomicAdd(&tri[u0], 1); atomicAdd(&tri[u1], 1);
        atomicAdd(&tri[u2], 1); atomicAdd(&tri[u3], 1);
        atomicAdd(&tri[u4], 1); atomicAdd(&tri[u5], 1);
        atomicAdd(&tri[u6], 1); atomicAdd(&tri[u7], 1);
    }
    __syncthreads();

    // ---- export: int4 LDS reads, packed bf16 (uint2) global stores ----
    float bsum = 0.0f, tsum = 0.0f;
    __hip_bfloat16* arow = Abi + row * KP_BI;
    for (int g = wpar * 64 + lane; g < KP_BI / 4; g += 128) {   // 280 groups
        uint2 pk{0, 0};
        if (g < NBI_P / 4) {               // bins 4g..4g+3 readable
            int4 v = *(const int4*)&bi[4 * g];
            float f0, f1, f2, f3;
            int b = 4 * g;
            f0 = (b + 0 >= 33 && (b + 0) % 33 != 0 && b + 0 < NBI) ? (float)v.x : 0.0f;
            f1 = (b + 1 >= 33 && (b + 1) % 33 != 0 && b + 1 < NBI) ? (float)v.y : 0.0f;
            f2 = (b + 2 >= 33 && (b + 2) % 33 != 0 && b + 2 < NBI) ? (float)v.z : 0.0f;
            f3 = (b + 3 >= 33 && (b + 3) % 33 != 0 && b + 3 < NBI) ? (float)v.w : 0.0f;
            bsum += f0 + f1 + f2 + f3;
            pk.x = f2bf(f0) | (f2bf(f1) << 16);
            pk.y = f2bf(f2) | (f2bf(f3) << 16);
        }
        *(uint2*)(arow + 4 * g) = pk;
    }
    {
        const int g = wpar * 64 + lane;    // exactly 128 groups of 4
        int4 v = *(const int4*)&tri[4 * g];
        float f0 = (float)v.x, f1 = (float)v.y, f2 = (float)v.z, f3 = (float)v.w;
        tsum += f0 + f1 + f2 + f3;
        uint2 pk;
        pk.x = f2bf(f0) | (f2bf(f1) << 16);
        pk.y = f2bf(f2) | (f2bf(f3) << 16);
        *(uint2*)(Atri + row * NTRI + 4 * g) = pk;
    }
    #pragma unroll
    for (int s = 32; s; s >>= 1) {
        bsum += __shfl_xor(bsum, s, 64);
        tsum += __shfl_xor(tsum, s, 64);
    }
    if (lane == 0) { s_ps[wrow][wpar][0] = bsum; s_ps[wrow][wpar][1] = tsum; }
    __syncthreads();
    if (tid < 2) {
        float bs = s_ps[tid][0][0] + s_ps[tid][1][0];
        float ts = s_ps[tid][0][1] + s_ps[tid][1][1];
        size_t r2 = ((size_t)blockIdx.x * 2 + tid) * 2;
        inv[r2 + 0] = 1.0f / fmaxf(bs, 1.0f);
        inv[r2 + 1] = 1.0f / fmaxf(ts, 1.0f);
    }
}

// ============ K2: fused layer1 MFMA GEMM (BM=32, N=256) + relu/len + layer2 ============
template<int KP>
__device__ __forceinline__
void head_body(const __hip_bfloat16* __restrict__ A,
               const __hip_bfloat16* __restrict__ WT,
               const float* __restrict__ b1,
               const float* __restrict__ W2,
               const float* __restrict__ b2,
               const float* __restrict__ inv, const int invoff, const int headoff,
               float* __restrict__ out, const int m0,
               float (*sH)[HSTRIDE])
{
    const int wave = threadIdx.x >> 6;       // 8 waves
    const int lane = threadIdx.x & 63;
    const int wn   = wave * 32;
    const int fr   = lane & 15;
    const int kg   = lane >> 4;

    const __hip_bfloat16* A0 = A  + (size_t)(m0 + fr) * KP + kg * 8;
    const __hip_bfloat16* A1 = A0 + (size_t)16 * KP;
    const __hip_bfloat16* B0 = WT + (size_t)(wn + fr) * KP + kg * 8;
    const __hip_bfloat16* B1 = B0 + (size_t)16 * KP;

    f32x4 acc00 = {}, acc01 = {}, acc10 = {}, acc11 = {};
    #pragma unroll 4
    for (int k = 0; k < KP; k += 32) {
        short8 a0  = *(const short8*)(A0 + k);
        short8 a1  = *(const short8*)(A1 + k);
        short8 b0  = *(const short8*)(B0 + k);
        short8 b1v = *(const short8*)(B1 + k);
        acc00 = __builtin_amdgcn_mfma_f32_16x16x32_bf16(a0, b0,  acc00, 0, 0, 0);
        acc01 = __builtin_amdgcn_mfma_f32_16x16x32_bf16(a0, b1v, acc01, 0, 0, 0);
        acc10 = __builtin_amdgcn_mfma_f32_16x16x32_bf16(a1, b0,  acc10, 0, 0, 0);
        acc11 = __builtin_amdgcn_mfma_f32_16x16x32_bf16(a1, b1v, acc11, 0, 0, 0);
    }

    f32x4 accs[2][2] = { {acc00, acc01}, {acc10, acc11} };
    #pragma unroll
    for (int mf = 0; mf < 2; ++mf) {
        #pragma unroll
        for (int nf = 0; nf < 2; ++nf) {
            const int col = wn + nf * 16 + fr;
            const float bias = b1[col];
            #pragma unroll
            for (int r = 0; r < 4; ++r) {
                const int rl = mf * 16 + kg * 4 + r;
                const float iv = inv[(m0 + rl) * 2 + invoff];
                sH[rl][col] = fmaxf(fmaf(accs[mf][nf][r], iv, bias), 0.0f);
            }
        }
    }
    __syncthreads();

    const int r  = threadIdx.x >> 4;
    const int oo = threadIdx.x & 15;
    const float* hr = sH[r];
    float a0 = b2[oo], a1 = b2[oo + 16];
    #pragma unroll 8
    for (int j = 0; j < NHID; j += 4) {
        float4 h = *(const float4*)(hr + j);
        a0 = fmaf(h.x, W2[(j + 0) * 32 + oo], a0);
        a0 = fmaf(h.y, W2[(j + 1) * 32 + oo], a0);
        a0 = fmaf(h.z, W2[(j + 2) * 32 + oo], a0);
        a0 = fmaf(h.w, W2[(j + 3) * 32 + oo], a0);
        a1 = fmaf(h.x, W2[(j + 0) * 32 + oo + 16], a1);
        a1 = fmaf(h.y, W2[(j + 1) * 32 + oo + 16], a1);
        a1 = fmaf(h.z, W2[(j + 2) * 32 + oo + 16], a1);
        a1 = fmaf(h.w, W2[(j + 3) * 32 + oo + 16], a1);
    }
    const size_t ro = (size_t)(m0 + r) * 64 + headoff;
    out[ro + oo]      = a0;
    out[ro + oo + 16] = a1;
}

__global__ __launch_bounds__(512, 1)
void gemm_fused(const __hip_bfloat16* __restrict__ Abi,
                const __hip_bfloat16* __restrict__ WbT,
                const float* __restrict__ bb1,
                const float* __restrict__ Wb2, const float* __restrict__ bb2,
                const __hip_bfloat16* __restrict__ Atri,
                const __hip_bfloat16* __restrict__ WtT,
                const float* __restrict__ bt1,
                const float* __restrict__ Wt2, const float* __restrict__ bt2,
                const float* __restrict__ inv,
                float* __restrict__ out)
{
    __shared__ float sH[32][HSTRIDE];
    // XCD-aware bijective swizzle: 256 blocks, 8 XCDs, 32 per XCD
    const int bid = (blockIdx.x & 7) * 32 + (blockIdx.x >> 3);
    if (bid < NROWS / 32) {
        head_body<KP_BI>(Abi, WbT, bb1, Wb2, bb2, inv, 0, 0,  out, bid * 32, sH);
    } else {
        head_body<NTRI>(Atri, WtT, bt1, Wt2, bt2, inv, 1, 32, out, (bid - NROWS / 32) * 32, sH);
    }
}

// ============ launcher ============
extern "C" void kernel_launch(void* const* d_in, const int* in_sizes, int n_in,
                              void* d_out, int out_size, void* d_ws, size_t ws_size,
                              hipStream_t stream) {
    const int*   src = (const int*)  d_in[0];
    const float* Wb1 = (const float*)d_in[1];
    const float* bb1 = (const float*)d_in[2];
    const float* Wb2 = (const float*)d_in[3];
    const float* bb2 = (const float*)d_in[4];
    const float* Wt1 = (const float*)d_in[5];
    const float* bt1 = (const float*)d_in[6];
    const float* Wt2 = (const float*)d_in[7];
    const float* bt2 = (const float*)d_in[8];
    float* outp = (float*)d_out;

    const int B = in_sizes[0] / TOK_S;           // 4096 rows

    char* ws = (char*)d_ws;
    __hip_bfloat16* Abi  = (__hip_bfloat16*)(ws);
    __hip_bfloat16* Atri = (__hip_bfloat16*)(ws + (size_t)B * KP_BI * 2);
    char* ws2 = ws + (size_t)B * KP_BI * 2 + (size_t)B * NTRI * 2;
    __hip_bfloat16* WbT  = (__hip_bfloat16*)(ws2);
    __hip_bfloat16* WtT  = (__hip_bfloat16*)(ws2 + (size_t)NHID * KP_BI * 2);
    float* inv = (float*)(ws2 + (size_t)NHID * KP_BI * 2 + (size_t)NHID * NTRI * 2);

    hist_trans<<<HIST_BLKS + TRANS_BLKS, 256, 0, stream>>>(
        src, Wb1, Wt1, Abi, Atri, WbT, WtT, inv);

    gemm_fused<<<2 * (B / 32), 512, 0, stream>>>(
        Abi, WbT, bb1, Wb2, bb2, Atri, WtT, bt1, Wt2, bt2, inv, outp);
}